// Round 6
// baseline (328.146 us; speedup 1.0000x reference)
//
#include <hip/hip_runtime.h>
#include <math.h>

#define D_MODEL   1024
#define D_INNER   2048
#define HEADDIM   64
#define NHEADS    32
#define D_STATE   128
#define D_CONV    4
#define CONV_DIM  2304      // D_INNER + 2*D_STATE
#define D_IN_PROJ 4384      // 2*D_INNER + 2*D_STATE + NHEADS
#define NPAD      4608      // D_IN_PROJ padded to multiple of 256
#define LSEQ      2048
#define BATCH     2
#define NROWS     4096      // BATCH * LSEQ
#define NC        32        // chunks per batch (LSEQ / 64)

typedef __attribute__((ext_vector_type(8))) short short8_t;
typedef __attribute__((ext_vector_type(4))) float f32x4;

#define MFMA16(a, b, c) __builtin_amdgcn_mfma_f32_16x16x32_bf16(a, b, c, 0, 0, 0)

// async global->LDS, 16B per lane (dest is wave-uniform base + lane*16)
#define GLDS(g, l) __builtin_amdgcn_global_load_lds( \
    (const __attribute__((address_space(1))) unsigned int*)(g), \
    (__attribute__((address_space(3))) unsigned int*)(l), 16, 0, 0)

__device__ __forceinline__ unsigned short f2bf(float f) {
  union { float f; unsigned int u; } v; v.f = f;
  unsigned int u = v.u + 0x7FFFu + ((v.u >> 16) & 1u);
  return (unsigned short)(u >> 16);
}
__device__ __forceinline__ float bf2f(unsigned short h) {
  union { unsigned int u; float f; } v; v.u = ((unsigned int)h) << 16;
  return v.f;
}

// XOR-swizzled LDS helpers (bf16 storage, swizzle byte ^= (row&7)<<4)
__device__ __forceinline__ short8_t lds_frag(const unsigned short* base, int row,
                                             int col, int rowlen) {
  int off = (row * rowlen + col) * 2;
  off ^= (row & 7) << 4;
  return *reinterpret_cast<const short8_t*>(
      reinterpret_cast<const char*>(base) + off);
}
__device__ __forceinline__ void lds_w32(unsigned short* base, int row, int col,
                                        int rowlen, unsigned int val) {
  int off = (row * rowlen + col) * 2;
  off ^= (row & 7) << 4;
  *reinterpret_cast<unsigned int*>(reinterpret_cast<char*>(base) + off) = val;
}
__device__ __forceinline__ void lds_w16(unsigned short* base, int row, int col,
                                        int rowlen, unsigned short val) {
  int off = (row * rowlen + col) * 2;
  off ^= (row & 7) << 4;
  *reinterpret_cast<unsigned short*>(reinterpret_cast<char*>(base) + off) = val;
}
__device__ __forceinline__ unsigned short lds_r16(const unsigned short* base,
                                                  int row, int col, int rowlen) {
  int off = (row * rowlen + col) * 2;
  off ^= (row & 7) << 4;
  return *reinterpret_cast<const unsigned short*>(
      reinterpret_cast<const char*>(base) + off);
}

// ---------------------------------------------------------------------------
// in_proj GEMM, 8-phase schedule.  BM=128 x BN=256, BK=64, 8 waves (2M x 4N),
// per-wave 64x64 (acc[4][4]).  LDS: 2 buf x (A 128x64 + B 256x64) bf16 = 96KB.
// Per phase: ds_read frags | stage one 128x64 unit of next tile | s_barrier |
// setprio(1) 8 MFMA setprio(0) | [phase3: vmcnt(0)] | s_barrier.
// Writes bf16 C + fp32 dtraw side-channel for the last 32 cols.
// ---------------------------------------------------------------------------
__global__ __launch_bounds__(512, 1) void gemm8_in(
    const unsigned short* __restrict__ A, const unsigned short* __restrict__ B,
    unsigned short* __restrict__ Cout, float* __restrict__ dtraw, int N, int K) {
  extern __shared__ unsigned short lds8[];
  const int tid = threadIdx.x;
  const int gx = gridDim.x;
  const int lin = blockIdx.y * gx + blockIdx.x;
  const int cpx = (gx * gridDim.y) >> 3;          // nwg % 8 == 0
  const int swz = (lin & 7) * cpx + (lin >> 3);
  const int row0 = (swz / gx) * 128;
  const int col0 = (swz % gx) * 256;

  const int l  = tid & 63;
  const int la = l & 15;
  const int lk = (l >> 4) * 8;
  const int w  = tid >> 6;
  const int wm = w >> 2;          // 0..1 -> rows wm*64
  const int wn = w & 3;           // 0..3 -> cols wn*64

  // staging slots: per 128x64 unit = 1024 x 16B slots; 2 per thread
  const int s0 = tid, s1 = tid + 512;
  const int r0 = s0 >> 3, j0 = ((s0 & 7) ^ (r0 & 7)) * 8;
  const int r1 = s1 >> 3, j1 = ((s1 & 7) ^ (r1 & 7)) * 8;

  f32x4 acc[4][4];
  #pragma unroll
  for (int i = 0; i < 4; ++i)
    #pragma unroll
    for (int j = 0; j < 4; ++j) acc[i][j] = (f32x4){0.f, 0.f, 0.f, 0.f};

  const int NT = K >> 6;

  // prologue: stage tile 0 (A unit + 2 B units)
  {
    unsigned short* dA = lds8;
    unsigned short* dB = lds8 + 8192;
    GLDS(&A[(size_t)(row0 + r0) * K + j0], &dA[s0 * 8]);
    GLDS(&A[(size_t)(row0 + r1) * K + j1], &dA[s1 * 8]);
    GLDS(&B[(size_t)(col0 + r0) * K + j0], &dB[s0 * 8]);
    GLDS(&B[(size_t)(col0 + r1) * K + j1], &dB[s1 * 8]);
    GLDS(&B[(size_t)(col0 + 128 + r0) * K + j0], &dB[8192 + s0 * 8]);
    GLDS(&B[(size_t)(col0 + 128 + r1) * K + j1], &dB[8192 + s1 * 8]);
  }
  asm volatile("s_waitcnt vmcnt(0)" ::: "memory");
  __builtin_amdgcn_s_barrier();

  for (int t = 0; t < NT; ++t) {
    const int cur = t & 1;
    const int k1 = (t + 1) << 6;
    const bool st = (t + 1 < NT);
    const unsigned short* aB = lds8 + cur * 24576;
    const unsigned short* bB = lds8 + cur * 24576 + 8192;
    unsigned short* dA = lds8 + (cur ^ 1) * 24576;
    unsigned short* dB = dA + 8192;

    #pragma unroll
    for (int q = 0; q < 4; ++q) {
      short8_t af[2], bfm[4][2];
      #pragma unroll
      for (int kk = 0; kk < 2; ++kk)
        af[kk] = lds_frag(aB, wm * 64 + q * 16 + la, kk * 32 + lk, 64);
      #pragma unroll
      for (int ni = 0; ni < 4; ++ni)
        #pragma unroll
        for (int kk = 0; kk < 2; ++kk)
          bfm[ni][kk] = lds_frag(bB, wn * 64 + ni * 16 + la, kk * 32 + lk, 64);
      if (q == 0 && st) {
        GLDS(&A[(size_t)(row0 + r0) * K + k1 + j0], &dA[s0 * 8]);
        GLDS(&A[(size_t)(row0 + r1) * K + k1 + j1], &dA[s1 * 8]);
      }
      if (q == 1 && st) {
        GLDS(&B[(size_t)(col0 + r0) * K + k1 + j0], &dB[s0 * 8]);
        GLDS(&B[(size_t)(col0 + r1) * K + k1 + j1], &dB[s1 * 8]);
      }
      if (q == 2 && st) {
        GLDS(&B[(size_t)(col0 + 128 + r0) * K + k1 + j0], &dB[8192 + s0 * 8]);
        GLDS(&B[(size_t)(col0 + 128 + r1) * K + k1 + j1], &dB[8192 + s1 * 8]);
      }
      __builtin_amdgcn_s_barrier();
      __builtin_amdgcn_s_setprio(1);
      #pragma unroll
      for (int ni = 0; ni < 4; ++ni)
        #pragma unroll
        for (int kk = 0; kk < 2; ++kk)
          acc[q][ni] = MFMA16(af[kk], bfm[ni][kk], acc[q][ni]);
      __builtin_amdgcn_s_setprio(0);
      if (q == 3) asm volatile("s_waitcnt vmcnt(0)" ::: "memory");
      __builtin_amdgcn_s_barrier();
    }
  }

  #pragma unroll
  for (int ni = 0; ni < 4; ++ni) {
    int gn = col0 + wn * 64 + ni * 16 + la;
    if (gn < N) {
      #pragma unroll
      for (int mi = 0; mi < 4; ++mi)
        #pragma unroll
        for (int r = 0; r < 4; ++r) {
          int gm = row0 + wm * 64 + mi * 16 + (l >> 4) * 4 + r;
          Cout[(size_t)gm * N + gn] = f2bf(acc[mi][ni][r]);
          if (gn >= N - 32)
            dtraw[(size_t)gm * 32 + (gn - (N - 32))] = acc[mi][ni][r];
        }
    }
  }
}

// ---------------------------------------------------------------------------
// out_proj GEMM (NT, fp32 C) — known-good 2-phase 128^2 kernel (256 WGs fills
// the chip exactly; a 256^2 grid would be 64 WGs = 25% of CUs).
// ---------------------------------------------------------------------------
__global__ __launch_bounds__(256) void gemm_bf16(
    const unsigned short* __restrict__ A, const unsigned short* __restrict__ B,
    float* __restrict__ C, int N, int K) {
  __shared__ unsigned short sA[128 * 64];
  __shared__ unsigned short sB[128 * 64];
  const int tid = threadIdx.x;
  const int lin = blockIdx.y * gridDim.x + blockIdx.x;
  const int cpx = (gridDim.x * gridDim.y) >> 3;
  const int swz = (lin & 7) * cpx + (lin >> 3);
  const int row0 = (swz / gridDim.x) * 128;
  const int col0 = (swz % gridDim.x) * 128;

  const int l  = tid & 63;
  const int la = l & 15;
  const int lk = (l >> 4) * 8;
  const int w  = tid >> 6;
  const int wr = (w >> 1) * 64;
  const int wc = (w & 1) * 64;

  f32x4 acc[4][4];
  #pragma unroll
  for (int i = 0; i < 4; ++i)
    #pragma unroll
    for (int j = 0; j < 4; ++j) acc[i][j] = (f32x4){0.f, 0.f, 0.f, 0.f};

  for (int k0 = 0; k0 < K; k0 += 64) {
    __syncthreads();
    #pragma unroll
    for (int i = 0; i < 4; ++i) {
      int s = i * 256 + tid;
      int r = s >> 3;
      int j = s & 7;
      int jc = j ^ (r & 7);
      GLDS(&A[(size_t)(row0 + r) * K + k0 + jc * 8], &sA[s * 8]);
      GLDS(&B[(size_t)(col0 + r) * K + k0 + jc * 8], &sB[s * 8]);
    }
    __syncthreads();

    #pragma unroll
    for (int kk = 0; kk < 2; ++kk) {
      short8_t af[4], bfr[4];
      #pragma unroll
      for (int mi = 0; mi < 4; ++mi)
        af[mi] = lds_frag(sA, wr + mi * 16 + la, kk * 32 + lk, 64);
      #pragma unroll
      for (int ni = 0; ni < 4; ++ni)
        bfr[ni] = lds_frag(sB, wc + ni * 16 + la, kk * 32 + lk, 64);
      #pragma unroll
      for (int mi = 0; mi < 4; ++mi)
        #pragma unroll
        for (int ni = 0; ni < 4; ++ni)
          acc[mi][ni] = MFMA16(af[mi], bfr[ni], acc[mi][ni]);
    }
  }

  #pragma unroll
  for (int mi = 0; mi < 4; ++mi)
    #pragma unroll
    for (int ni = 0; ni < 4; ++ni)
      #pragma unroll
      for (int r = 0; r < 4; ++r) {
        int gm = row0 + wr + mi * 16 + (l >> 4) * 4 + r;
        int gn = col0 + wc + ni * 16 + la;
        C[(size_t)gm * N + gn] = acc[mi][ni][r];
      }
}

// ---------------------------------------------------------------------------
// fp32 -> bf16 converts
// ---------------------------------------------------------------------------
__global__ __launch_bounds__(256) void cvt_bf16_kernel(
    const float* __restrict__ src, unsigned short* __restrict__ dst) {
  long i = (long)blockIdx.x * 256 + threadIdx.x;
  float4 a = *reinterpret_cast<const float4*>(&src[i * 8]);
  float4 b = *reinterpret_cast<const float4*>(&src[i * 8 + 4]);
  short8_t o;
  o[0] = (short)f2bf(a.x); o[1] = (short)f2bf(a.y);
  o[2] = (short)f2bf(a.z); o[3] = (short)f2bf(a.w);
  o[4] = (short)f2bf(b.x); o[5] = (short)f2bf(b.y);
  o[6] = (short)f2bf(b.z); o[7] = (short)f2bf(b.w);
  *reinterpret_cast<short8_t*>(&dst[i * 8]) = o;
}

// in_proj_w (4384 x 1024) -> bf16 padded to NPAD rows (zeros)
__global__ __launch_bounds__(256) void cvt_w_kernel(
    const float* __restrict__ w, unsigned short* __restrict__ wbf) {
  long i = (long)blockIdx.x * 256 + threadIdx.x;   // over NPAD*128
  int row = (int)(i >> 7);
  int c8  = (int)(i & 127) << 3;
  short8_t o = {0, 0, 0, 0, 0, 0, 0, 0};
  if (row < D_IN_PROJ) {
    float4 a = *reinterpret_cast<const float4*>(&w[(size_t)row * D_MODEL + c8]);
    float4 b = *reinterpret_cast<const float4*>(&w[(size_t)row * D_MODEL + c8 + 4]);
    o[0] = (short)f2bf(a.x); o[1] = (short)f2bf(a.y);
    o[2] = (short)f2bf(a.z); o[3] = (short)f2bf(a.w);
    o[4] = (short)f2bf(b.x); o[5] = (short)f2bf(b.y);
    o[6] = (short)f2bf(b.z); o[7] = (short)f2bf(b.w);
  }
  *reinterpret_cast<short8_t*>(&wbf[(size_t)row * D_MODEL + c8]) = o;
}

// ---------------------------------------------------------------------------
// depthwise causal conv (K=4) + bias + silu.  l-strip register rolling.
// ---------------------------------------------------------------------------
__global__ __launch_bounds__(256) void conv_silu_kernel(
    const unsigned short* __restrict__ zxb, const float* __restrict__ conv_w,
    const float* __restrict__ conv_b, unsigned short* __restrict__ xconv) {
  const int c  = blockIdx.x * 256 + threadIdx.x;
  const int l0 = blockIdx.y * 128;
  const int b  = blockIdx.z;
  const unsigned short* src = zxb + ((size_t)b * LSEQ) * D_IN_PROJ + D_INNER + c;
  const float w0 = conv_w[c * 4 + 0], w1 = conv_w[c * 4 + 1];
  const float w2 = conv_w[c * 4 + 2], w3 = conv_w[c * 4 + 3];
  const float bia = conv_b[c];
  float x0 = (l0 >= 3) ? bf2f(src[(size_t)(l0 - 3) * D_IN_PROJ]) : 0.f;
  float x1 = (l0 >= 2) ? bf2f(src[(size_t)(l0 - 2) * D_IN_PROJ]) : 0.f;
  float x2 = (l0 >= 1) ? bf2f(src[(size_t)(l0 - 1) * D_IN_PROJ]) : 0.f;
  unsigned short* dst = xconv + ((size_t)(b * LSEQ + l0)) * CONV_DIM + c;
  #pragma unroll 4
  for (int i = 0; i < 128; ++i) {
    float x3 = bf2f(src[(size_t)(l0 + i) * D_IN_PROJ]);
    float acc = fmaf(w3, x3, fmaf(w2, x2, fmaf(w1, x1, fmaf(w0, x0, bia))));
    float s = acc / (1.f + expf(-acc));
    dst[(size_t)i * CONV_DIM] = f2bf(s);
    x0 = x1; x1 = x2; x2 = x3;
  }
}

// ---------------------------------------------------------------------------
// fused: dt = softplus(dtraw + bias); per-chunk cumsum of dt*A.
// one wave per (b,c,h); writes dt_s and cumL.
// ---------------------------------------------------------------------------
__global__ __launch_bounds__(256) void cumsum_kernel(
    const float* __restrict__ dtraw, const float* __restrict__ dt_bias,
    const float* __restrict__ A_log, float* __restrict__ dt_s,
    float* __restrict__ cumL) {
  int u = blockIdx.x * 4 + (threadIdx.x >> 6);
  int lane = threadIdx.x & 63;
  int h = u & 31;
  int bc = u >> 5;
  int row = bc * 64 + lane;
  float xr = dtraw[(size_t)row * 32 + h] + dt_bias[h];
  float dt = (xr > 20.f) ? xr : log1pf(expf(xr));
  dt_s[(size_t)row * NHEADS + h] = dt;
  float A = -expf(A_log[h]);
  float a = dt * A;
  #pragma unroll
  for (int off = 1; off < 64; off <<= 1) {
    float v = __shfl_up(a, off);
    if (lane >= off) a += v;
  }
  cumL[(size_t)u * 64 + lane] = a;
}

// ---------------------------------------------------------------------------
// chunk state: S^T[p][n] = sum_s w_s x[s][p] B[s][n]
// ---------------------------------------------------------------------------
__global__ __launch_bounds__(256) void chunkstate_kernel(
    const unsigned short* __restrict__ xconv, const float* __restrict__ dt_s,
    const float* __restrict__ cumL, unsigned short* __restrict__ S) {
  const int bi = blockIdx.x;
  const int h  = bi & 31;
  const int bc = bi >> 5;
  const int row0 = bc * 64;
  const int tid = threadIdx.x;

  __shared__ unsigned short sBT[128 * 64];   // [n][s]
  __shared__ unsigned short sXT[64 * 64];    // [p][s]  (w-weighted)
  __shared__ float sw[64];

  if (tid < 64) {
    float L   = cumL[(size_t)bi * 64 + tid];
    float L63 = cumL[(size_t)bi * 64 + 63];
    sw[tid] = dt_s[(size_t)(row0 + tid) * NHEADS + h] * expf(L63 - L);
  }
  __syncthreads();

  #pragma unroll
  for (int i = 0; i < 16; ++i) {
    int idx = tid + i * 256;
    int s = idx >> 6, n2 = idx & 63;
    unsigned int v = *reinterpret_cast<const unsigned int*>(
        &xconv[(size_t)(row0 + s) * CONV_DIM + D_INNER + n2 * 2]);
    lds_w16(sBT, n2 * 2 + 0, s, 64, (unsigned short)v);
    lds_w16(sBT, n2 * 2 + 1, s, 64, (unsigned short)(v >> 16));
  }
  #pragma unroll
  for (int i = 0; i < 16; ++i) {
    int idx = tid + i * 256;
    int s = idx >> 6, p = idx & 63;
    float xv = bf2f(xconv[(size_t)(row0 + s) * CONV_DIM + h * HEADDIM + p]);
    lds_w16(sXT, p, s, 64, f2bf(xv * sw[s]));
  }
  __syncthreads();

  const int w  = tid >> 6;
  const int l  = tid & 63;
  const int la = l & 15;
  const int lk = (l >> 4) * 8;

  f32x4 acc[8];
  #pragma unroll
  for (int i = 0; i < 8; ++i) acc[i] = (f32x4){0.f, 0.f, 0.f, 0.f};

  #pragma unroll
  for (int ks = 0; ks < 2; ++ks) {
    short8_t a = lds_frag(sXT, 16 * w + la, ks * 32 + lk, 64);
    #pragma unroll
    for (int ni = 0; ni < 8; ++ni) {
      short8_t b = lds_frag(sBT, ni * 16 + la, ks * 32 + lk, 64);
      acc[ni] = MFMA16(a, b, acc[ni]);
    }
  }

  unsigned short* dst = S + (size_t)bi * (HEADDIM * D_STATE);
  #pragma unroll
  for (int ni = 0; ni < 8; ++ni)
    #pragma unroll
    for (int r = 0; r < 4; ++r) {
      int p = 16 * w + (l >> 4) * 4 + r;
      int n = ni * 16 + la;
      dst[p * D_STATE + n] = f2bf(acc[ni][r]);
    }
}

// ---------------------------------------------------------------------------
// H recurrence, elementwise; in place S -> Hprev.
// ---------------------------------------------------------------------------
__global__ __launch_bounds__(256) void hscan_kernel(
    unsigned short* __restrict__ S, const float* __restrict__ cumL) {
  const int g  = blockIdx.x;
  const int bh = g >> 5;
  const int b  = bh >> 5;
  const int h  = bh & 31;
  const int e  = (g & 31) * 256 + threadIdx.x;

  float H = 0.f;
  #pragma unroll 4
  for (int c = 0; c < NC; ++c) {
    size_t u = (size_t)((b * NC + c) * NHEADS + h);
    float dA = expf(cumL[u * 64 + 63]);
    unsigned short sv = S[u * (HEADDIM * D_STATE) + e];
    S[u * (HEADDIM * D_STATE) + e] = f2bf(H);
    H = dA * H + bf2f(sv);
  }
}

// ---------------------------------------------------------------------------
// fused chunk kernel -> y (bf16)
// ---------------------------------------------------------------------------
__global__ __launch_bounds__(256) void chunk_kernel(
    const unsigned short* __restrict__ xconv, const float* __restrict__ dt_s,
    const float* __restrict__ cumL, const unsigned short* __restrict__ Hprev,
    const float* __restrict__ D_skip, unsigned short* __restrict__ y) {
  const int bi = blockIdx.x;
  const int h  = bi & 31;
  const int bc = bi >> 5;
  const int row0 = bc * 64;
  const int tid = threadIdx.x;

  __shared__ unsigned short sC[64 * 128];
  __shared__ unsigned short sB[64 * 128];
  __shared__ unsigned short sXT[64 * 64];
  __shared__ unsigned short sP[64 * 64];
  __shared__ float sL[64], sdt[64], seL[64];

  if (tid < 64) {
    float L = cumL[(size_t)bi * 64 + tid];
    sL[tid]  = L;
    seL[tid] = expf(L);
    sdt[tid] = dt_s[(size_t)(row0 + tid) * NHEADS + h];
  }

  #pragma unroll
  for (int i = 0; i < 8; ++i) {
    int idx = tid + i * 256;
    int r = idx >> 5, q = idx & 31;
    short8_t v = *reinterpret_cast<const short8_t*>(
        &xconv[(size_t)(row0 + r) * CONV_DIM + D_INNER + q * 8]);
    unsigned int u0 = (unsigned int)(unsigned short)v[0] |
                      ((unsigned int)(unsigned short)v[1] << 16);
    unsigned int u1 = (unsigned int)(unsigned short)v[2] |
                      ((unsigned int)(unsigned short)v[3] << 16);
    unsigned int u2 = (unsigned int)(unsigned short)v[4] |
                      ((unsigned int)(unsigned short)v[5] << 16);
    unsigned int u3 = (unsigned int)(unsigned short)v[6] |
                      ((unsigned int)(unsigned short)v[7] << 16);
    unsigned short* dstb = (q < 16) ? sB : sC;
    int cq = (q & 15) * 8;
    lds_w32(dstb, r, cq + 0, 128, u0);
    lds_w32(dstb, r, cq + 2, 128, u1);
    lds_w32(dstb, r, cq + 4, 128, u2);
    lds_w32(dstb, r, cq + 6, 128, u3);
  }
  #pragma unroll
  for (int i = 0; i < 16; ++i) {
    int idx = tid + i * 256;
    int s = idx >> 6, p = idx & 63;
    lds_w16(sXT, p, s, 64,
            xconv[(size_t)(row0 + s) * CONV_DIM + h * HEADDIM + p]);
  }
  __syncthreads();

  const int w  = tid >> 6;
  const int l  = tid & 63;
  const int la = l & 15;
  const int lk = (l >> 4) * 8;
  const int t0 = 16 * w;

  f32x4 g[4];
  #pragma unroll
  for (int i = 0; i < 4; ++i) g[i] = (f32x4){0.f, 0.f, 0.f, 0.f};
  #pragma unroll
  for (int ks = 0; ks < 4; ++ks) {
    short8_t a = lds_frag(sC, t0 + la, ks * 32 + lk, 128);
    #pragma unroll
    for (int si = 0; si < 4; ++si) {
      short8_t b = lds_frag(sB, si * 16 + la, ks * 32 + lk, 128);
      g[si] = MFMA16(a, b, g[si]);
    }
  }
  #pragma unroll
  for (int si = 0; si < 4; ++si)
    #pragma unroll
    for (int r = 0; r < 4; ++r) {
      int t = t0 + (l >> 4) * 4 + r;
      int s = si * 16 + la;
      float m = 0.f;
      if (s <= t) m = expf(sL[t] - sL[s]) * sdt[s] * g[si][r];
      lds_w16(sP, t, s, 64, f2bf(m));
    }
  __syncthreads();

  f32x4 o[4];
  #pragma unroll
  for (int i = 0; i < 4; ++i) o[i] = (f32x4){0.f, 0.f, 0.f, 0.f};

  const unsigned short* hb = Hprev + (size_t)bi * (HEADDIM * D_STATE);
  #pragma unroll
  for (int ks = 0; ks < 4; ++ks) {
    short8_t a = lds_frag(sC, t0 + la, ks * 32 + lk, 128);
    #pragma unroll
    for (int si = 0; si < 4; ++si) {
      int p = si * 16 + la;
      short8_t b = *reinterpret_cast<const short8_t*>(
          &hb[p * D_STATE + ks * 32 + lk]);
      o[si] = MFMA16(a, b, o[si]);
    }
  }
  #pragma unroll
  for (int si = 0; si < 4; ++si)
    #pragma unroll
    for (int r = 0; r < 4; ++r) {
      int t = t0 + (l >> 4) * 4 + r;
      o[si][r] *= seL[t];
    }
  #pragma unroll
  for (int ks = 0; ks < 2; ++ks) {
    short8_t a = lds_frag(sP, t0 + la, ks * 32 + lk, 64);
    #pragma unroll
    for (int si = 0; si < 4; ++si) {
      short8_t b = lds_frag(sXT, si * 16 + la, ks * 32 + lk, 64);
      o[si] = MFMA16(a, b, o[si]);
    }
  }
  const float Dh = D_skip[h];
  #pragma unroll
  for (int si = 0; si < 4; ++si)
    #pragma unroll
    for (int r = 0; r < 4; ++r) {
      int t = t0 + (l >> 4) * 4 + r;
      int p = si * 16 + la;
      float xv = bf2f(lds_r16(sXT, p, t, 64));
      y[(size_t)(row0 + t) * D_INNER + h * HEADDIM + p] = f2bf(o[si][r] + Dh * xv);
    }
}

// ---------------------------------------------------------------------------
// y(bf16) = y * silu(z bf16); RMSNorm; in-place, short8 vectorized
// ---------------------------------------------------------------------------
__global__ __launch_bounds__(256) void gate_rms_kernel(
    unsigned short* __restrict__ y, const unsigned short* __restrict__ zxb,
    const float* __restrict__ norm_w) {
  const int row = blockIdx.x;
  const int tid = threadIdx.x;
  short8_t zv = *reinterpret_cast<const short8_t*>(
      &zxb[(size_t)row * D_IN_PROJ + tid * 8]);
  short8_t yv = *reinterpret_cast<short8_t*>(
      &y[(size_t)row * D_INNER + tid * 8]);
  float v[8];
  float acc = 0.f;
  #pragma unroll
  for (int i = 0; i < 8; ++i) {
    float z  = bf2f((unsigned short)zv[i]);
    float ys = bf2f((unsigned short)yv[i]);
    float gz = z / (1.f + expf(-z));
    float val = ys * gz;
    v[i] = val;
    acc = fmaf(val, val, acc);
  }
  #pragma unroll
  for (int off = 32; off; off >>= 1) acc += __shfl_xor(acc, off);
  __shared__ float wsum[4];
  if ((tid & 63) == 0) wsum[tid >> 6] = acc;
  __syncthreads();
  float total = wsum[0] + wsum[1] + wsum[2] + wsum[3];
  float scale = rsqrtf(total / (float)D_INNER + 1e-5f);
  short8_t o;
  #pragma unroll
  for (int i = 0; i < 8; ++i)
    o[i] = (short)f2bf(v[i] * scale * norm_w[tid * 8 + i]);
  *reinterpret_cast<short8_t*>(&y[(size_t)row * D_INNER + tid * 8]) = o;
}

// ---------------------------------------------------------------------------
// LayerNorm + residual
// ---------------------------------------------------------------------------
__global__ __launch_bounds__(256) void ln_kernel(
    const float* __restrict__ o, const float* __restrict__ x,
    const float* __restrict__ lng, const float* __restrict__ lnb,
    float* __restrict__ out) {
  const int row = blockIdx.x;
  const int tid = threadIdx.x;
  float v[4];
  float s = 0.f, s2 = 0.f;
  #pragma unroll
  for (int i = 0; i < 4; ++i) {
    int d = i * 256 + tid;
    float t = o[(size_t)row * D_MODEL + d];
    v[i] = t;
    s += t;
    s2 = fmaf(t, t, s2);
  }
  #pragma unroll
  for (int off = 32; off; off >>= 1) {
    s  += __shfl_xor(s, off);
    s2 += __shfl_xor(s2, off);
  }
  __shared__ float sa[4], sb[4];
  if ((tid & 63) == 0) { sa[tid >> 6] = s; sb[tid >> 6] = s2; }
  __syncthreads();
  s  = sa[0] + sa[1] + sa[2] + sa[3];
  s2 = sb[0] + sb[1] + sb[2] + sb[3];
  float mu  = s / (float)D_MODEL;
  float var = s2 / (float)D_MODEL - mu * mu;
  float inv = rsqrtf(var + 1e-5f);
  #pragma unroll
  for (int i = 0; i < 4; ++i) {
    int d = i * 256 + tid;
    out[(size_t)row * D_MODEL + d] =
        (v[i] - mu) * inv * lng[d] + lnb[d] + x[(size_t)row * D_MODEL + d];
  }
}

// ---------------------------------------------------------------------------
extern "C" void kernel_launch(void* const* d_in, const int* in_sizes, int n_in,
                              void* d_out, int out_size, void* d_ws, size_t ws_size,
                              hipStream_t stream) {
  const float* x         = (const float*)d_in[0];
  const float* in_proj_w = (const float*)d_in[1];
  const float* conv_w    = (const float*)d_in[2];
  const float* conv_b    = (const float*)d_in[3];
  const float* dt_bias   = (const float*)d_in[4];
  const float* A_log     = (const float*)d_in[5];
  const float* D_skip    = (const float*)d_in[6];
  const float* norm_w    = (const float*)d_in[7];
  const float* out_w     = (const float*)d_in[8];
  const float* ln_g      = (const float*)d_in[9];
  const float* ln_b      = (const float*)d_in[10];
  float* out = (float*)d_out;

  char* ws = (char*)d_ws;
  unsigned short* zxb   = (unsigned short*)ws;                       // 4096*4384 bf16
  float* outpre         = (float*)ws;                                // alias (dead z)
  char* p = ws + (size_t)NROWS * D_IN_PROJ * 2;
  float* dtraw = (float*)p;            p += (size_t)NROWS * 32 * 4;
  float* dt_s  = (float*)p;            p += (size_t)NROWS * 32 * 4;
  float* cumL  = (float*)p;            p += (size_t)BATCH * NC * NHEADS * 64 * 4;
  unsigned short* xconv = (unsigned short*)p;  p += (size_t)NROWS * CONV_DIM * 2;
  unsigned short* schp  = (unsigned short*)p;  p += (size_t)BATCH * NC * NHEADS * HEADDIM * D_STATE * 2;
  unsigned short* ybuf  = (unsigned short*)p;  p += (size_t)NROWS * D_INNER * 2;
  unsigned short* xbf   = (unsigned short*)p;  p += (size_t)NROWS * D_MODEL * 2;
  unsigned short* wbf   = (unsigned short*)p;  p += (size_t)NPAD * D_MODEL * 2;
  unsigned short* owbf  = (unsigned short*)p;

  // allow 96KB dynamic LDS for the 8-phase GEMM (ignore error if unsupported)
  (void)hipFuncSetAttribute(reinterpret_cast<const void*>(&gemm8_in),
                            hipFuncAttributeMaxDynamicSharedMemorySize, 98304);

  // 0. converts
  cvt_bf16_kernel<<<dim3(NROWS * D_MODEL / 8 / 256), dim3(256), 0, stream>>>(
      x, xbf);
  cvt_w_kernel<<<dim3(NPAD * 128 / 256), dim3(256), 0, stream>>>(
      in_proj_w, wbf);
  cvt_bf16_kernel<<<dim3(D_MODEL * D_INNER / 8 / 256), dim3(256), 0, stream>>>(
      out_w, owbf);

  // 1. in_proj GEMM (8-phase, bf16 out + fp32 dtraw side-channel)
  gemm8_in<<<dim3(NPAD / 256, NROWS / 128), dim3(512), 98304, stream>>>(
      xbf, wbf, zxb, dtraw, D_IN_PROJ, D_MODEL);

  // 2. conv + silu (bf16 in/out, l-strip)
  conv_silu_kernel<<<dim3(CONV_DIM / 256, LSEQ / 128, BATCH), dim3(256), 0, stream>>>(
      zxb, conv_w, conv_b, xconv);

  // 3. fused dt + per-chunk cumsum
  cumsum_kernel<<<dim3(BATCH * NC * NHEADS / 4), dim3(256), 0, stream>>>(
      dtraw, dt_bias, A_log, dt_s, cumL);

  // 4. chunk states S (bf16)
  chunkstate_kernel<<<dim3(BATCH * NC * NHEADS), dim3(256), 0, stream>>>(
      xconv, dt_s, cumL, schp);

  // 5. H recurrence (in place S -> Hprev)
  hscan_kernel<<<dim3(BATCH * NHEADS * 32), dim3(256), 0, stream>>>(
      schp, cumL);

  // 6. fused chunk kernel (writes ybuf bf16)
  chunk_kernel<<<dim3(BATCH * NC * NHEADS), dim3(256), 0, stream>>>(
      xconv, dt_s, cumL, schp, D_skip, ybuf);

  // 7. gate + rmsnorm (in-place bf16)
  gate_rms_kernel<<<dim3(NROWS), dim3(256), 0, stream>>>(
      ybuf, zxb, norm_w);

  // 8. out_proj GEMM (fp32 out into outpre, aliasing dead zxb)
  gemm_bf16<<<dim3(D_MODEL / 128, NROWS / 128), dim3(256), 0, stream>>>(
      ybuf, owbf, outpre, D_MODEL, D_INNER);

  // 9. layernorm + residual
  ln_kernel<<<dim3(NROWS), dim3(256), 0, stream>>>(
      outpre, x, ln_g, ln_b, out);
}

// Round 7
// 298.838 us; speedup vs baseline: 1.0981x; 1.0981x over previous
//
#include <hip/hip_runtime.h>
#include <math.h>

#define D_MODEL   1024
#define D_INNER   2048
#define HEADDIM   64
#define NHEADS    32
#define D_STATE   128
#define D_CONV    4
#define CONV_DIM  2304      // D_INNER + 2*D_STATE
#define D_IN_PROJ 4384      // 2*D_INNER + 2*D_STATE + NHEADS
#define NPAD      4480      // D_IN_PROJ padded to multiple of 128
#define LSEQ      2048
#define BATCH     2
#define NROWS     4096      // BATCH * LSEQ
#define NC        32        // chunks per batch (LSEQ / 64)

typedef __attribute__((ext_vector_type(8))) short short8_t;
typedef __attribute__((ext_vector_type(4))) float f32x4;

#define MFMA16(a, b, c) __builtin_amdgcn_mfma_f32_16x16x32_bf16(a, b, c, 0, 0, 0)

// async global->LDS, 16B per lane (dest is wave-uniform base + lane*16)
#define GLDS(g, l) __builtin_amdgcn_global_load_lds( \
    (const __attribute__((address_space(1))) unsigned int*)(g), \
    (__attribute__((address_space(3))) unsigned int*)(l), 16, 0, 0)

__device__ __forceinline__ unsigned short f2bf(float f) {
  union { float f; unsigned int u; } v; v.f = f;
  unsigned int u = v.u + 0x7FFFu + ((v.u >> 16) & 1u);
  return (unsigned short)(u >> 16);
}
__device__ __forceinline__ float bf2f(unsigned short h) {
  union { unsigned int u; float f; } v; v.u = ((unsigned int)h) << 16;
  return v.f;
}

// XOR-swizzled LDS helpers (bf16 storage, swizzle byte ^= (row&7)<<4)
__device__ __forceinline__ short8_t lds_frag(const unsigned short* base, int row,
                                             int col, int rowlen) {
  int off = (row * rowlen + col) * 2;
  off ^= (row & 7) << 4;
  return *reinterpret_cast<const short8_t*>(
      reinterpret_cast<const char*>(base) + off);
}
__device__ __forceinline__ void lds_w32(unsigned short* base, int row, int col,
                                        int rowlen, unsigned int val) {
  int off = (row * rowlen + col) * 2;
  off ^= (row & 7) << 4;
  *reinterpret_cast<unsigned int*>(reinterpret_cast<char*>(base) + off) = val;
}
__device__ __forceinline__ void lds_w16(unsigned short* base, int row, int col,
                                        int rowlen, unsigned short val) {
  int off = (row * rowlen + col) * 2;
  off ^= (row & 7) << 4;
  *reinterpret_cast<unsigned short*>(reinterpret_cast<char*>(base) + off) = val;
}
__device__ __forceinline__ unsigned short lds_r16(const unsigned short* base,
                                                  int row, int col, int rowlen) {
  int off = (row * rowlen + col) * 2;
  off ^= (row & 7) << 4;
  return *reinterpret_cast<const unsigned short*>(
      reinterpret_cast<const char*>(base) + off);
}

// ---------------------------------------------------------------------------
// bf16 MFMA GEMM (NT), double-buffered "proper 2-phase":
//   prologue: stage tile0; vmcnt(0); barrier
//   loop t:   ISSUE stage(t+1 -> buf^1); compute buf (ds_read+MFMA);
//             vmcnt(0); barrier           <- loads flew during compute
// 128x128 tile, BK=64, 4 waves, 64KB dynamic LDS (2 bufs), XCD swizzle.
// MODE 0: fp32 C.  MODE 1: bf16 C + fp32 dtraw side-channel (last 32 cols).
// ---------------------------------------------------------------------------
#define STAGE_TILE(bufA, bufB, kk0)                                        \
  do {                                                                     \
    _Pragma("unroll")                                                      \
    for (int i_ = 0; i_ < 4; ++i_) {                                       \
      int s_ = i_ * 256 + tid;                                             \
      int r_ = s_ >> 3;                                                    \
      int jc_ = ((s_ & 7) ^ (r_ & 7)) * 8;                                 \
      GLDS(&A[(size_t)(row0 + r_) * K + (kk0) + jc_], &(bufA)[s_ * 8]);    \
      GLDS(&B[(size_t)(col0 + r_) * K + (kk0) + jc_], &(bufB)[s_ * 8]);    \
    }                                                                      \
  } while (0)

template <int MODE>
__global__ __launch_bounds__(256) void gemm_db(
    const unsigned short* __restrict__ A, const unsigned short* __restrict__ B,
    void* __restrict__ Cout, float* __restrict__ dtraw, int N, int K) {
  extern __shared__ unsigned short lds[];
  const int tid = threadIdx.x;
  const int lin = blockIdx.y * gridDim.x + blockIdx.x;
  const int cpx = (gridDim.x * gridDim.y) >> 3;    // nwg % 8 == 0
  const int swz = (lin & 7) * cpx + (lin >> 3);
  const int row0 = (swz / gridDim.x) * 128;
  const int col0 = (swz % gridDim.x) * 128;

  const int l  = tid & 63;
  const int la = l & 15;
  const int lk = (l >> 4) * 8;
  const int w  = tid >> 6;
  const int wr = (w >> 1) * 64;
  const int wc = (w & 1) * 64;

  f32x4 acc[4][4];
  #pragma unroll
  for (int i = 0; i < 4; ++i)
    #pragma unroll
    for (int j = 0; j < 4; ++j) acc[i][j] = (f32x4){0.f, 0.f, 0.f, 0.f};

  const int NT = K >> 6;

  // prologue: stage tile 0 into buf 0
  {
    unsigned short* dA = lds;
    unsigned short* dB = lds + 8192;
    STAGE_TILE(dA, dB, 0);
  }
  asm volatile("s_waitcnt vmcnt(0)" ::: "memory");
  __builtin_amdgcn_s_barrier();

  for (int t = 0; t < NT; ++t) {
    const int cur = t & 1;
    // 1. issue next-tile loads FIRST (they fly during the MFMA block)
    if (t + 1 < NT) {
      unsigned short* dA = lds + (cur ^ 1) * 16384;
      unsigned short* dB = dA + 8192;
      STAGE_TILE(dA, dB, (t + 1) << 6);
    }
    // 2. compute current tile
    const unsigned short* aB = lds + cur * 16384;
    const unsigned short* bB = aB + 8192;
    #pragma unroll
    for (int kk = 0; kk < 2; ++kk) {
      short8_t af[4], bfr[4];
      #pragma unroll
      for (int mi = 0; mi < 4; ++mi)
        af[mi] = lds_frag(aB, wr + mi * 16 + la, kk * 32 + lk, 64);
      #pragma unroll
      for (int ni = 0; ni < 4; ++ni)
        bfr[ni] = lds_frag(bB, wc + ni * 16 + la, kk * 32 + lk, 64);
      #pragma unroll
      for (int mi = 0; mi < 4; ++mi)
        #pragma unroll
        for (int ni = 0; ni < 4; ++ni)
          acc[mi][ni] = MFMA16(af[mi], bfr[ni], acc[mi][ni]);
    }
    // 3. one drain + barrier per tile
    asm volatile("s_waitcnt vmcnt(0)" ::: "memory");
    __builtin_amdgcn_s_barrier();
  }

  #pragma unroll
  for (int mi = 0; mi < 4; ++mi)
    #pragma unroll
    for (int ni = 0; ni < 4; ++ni)
      #pragma unroll
      for (int r = 0; r < 4; ++r) {
        int gm = row0 + wr + mi * 16 + (l >> 4) * 4 + r;
        int gn = col0 + wc + ni * 16 + la;
        if (gn < N) {
          if constexpr (MODE == 0) {
            ((float*)Cout)[(size_t)gm * N + gn] = acc[mi][ni][r];
          } else {
            ((unsigned short*)Cout)[(size_t)gm * N + gn] = f2bf(acc[mi][ni][r]);
            if (gn >= N - 32)
              dtraw[(size_t)gm * 32 + (gn - (N - 32))] = acc[mi][ni][r];
          }
        }
      }
}

// ---------------------------------------------------------------------------
// all three fp32->bf16 converts in one launch:
//   region 1: x (4096x1024), region 2: in_proj_w padded to NPAD rows,
//   region 3: out_w (1024x2048)
// ---------------------------------------------------------------------------
__device__ __forceinline__ short8_t cvt8(const float* s) {
  float4 a = *reinterpret_cast<const float4*>(s);
  float4 b = *reinterpret_cast<const float4*>(s + 4);
  short8_t o;
  o[0] = (short)f2bf(a.x); o[1] = (short)f2bf(a.y);
  o[2] = (short)f2bf(a.z); o[3] = (short)f2bf(a.w);
  o[4] = (short)f2bf(b.x); o[5] = (short)f2bf(b.y);
  o[6] = (short)f2bf(b.z); o[7] = (short)f2bf(b.w);
  return o;
}

__global__ __launch_bounds__(256) void cvt_all_kernel(
    const float* __restrict__ x, const float* __restrict__ w,
    const float* __restrict__ ow, unsigned short* __restrict__ xbf,
    unsigned short* __restrict__ wbf, unsigned short* __restrict__ owbf) {
  const long n1 = (long)NROWS * D_MODEL / 8;     // 524288
  const long n2 = (long)NPAD * D_MODEL / 8;      // 573440
  long i = (long)blockIdx.x * 256 + threadIdx.x;
  if (i < n1) {
    *reinterpret_cast<short8_t*>(&xbf[i * 8]) = cvt8(&x[i * 8]);
  } else if (i < n1 + n2) {
    long j = i - n1;
    int row = (int)(j >> 7);
    int c8  = (int)(j & 127) << 3;
    short8_t o = {0, 0, 0, 0, 0, 0, 0, 0};
    if (row < D_IN_PROJ) o = cvt8(&w[(size_t)row * D_MODEL + c8]);
    *reinterpret_cast<short8_t*>(&wbf[(size_t)row * D_MODEL + c8]) = o;
  } else {
    long j = i - n1 - n2;
    *reinterpret_cast<short8_t*>(&owbf[j * 8]) = cvt8(&ow[j * 8]);
  }
}

// ---------------------------------------------------------------------------
// depthwise causal conv (K=4) + bias + silu.  l-strip register rolling.
// ---------------------------------------------------------------------------
__global__ __launch_bounds__(256) void conv_silu_kernel(
    const unsigned short* __restrict__ zxb, const float* __restrict__ conv_w,
    const float* __restrict__ conv_b, unsigned short* __restrict__ xconv) {
  const int c  = blockIdx.x * 256 + threadIdx.x;
  const int l0 = blockIdx.y * 128;
  const int b  = blockIdx.z;
  const unsigned short* src = zxb + ((size_t)b * LSEQ) * D_IN_PROJ + D_INNER + c;
  const float w0 = conv_w[c * 4 + 0], w1 = conv_w[c * 4 + 1];
  const float w2 = conv_w[c * 4 + 2], w3 = conv_w[c * 4 + 3];
  const float bia = conv_b[c];
  float x0 = (l0 >= 3) ? bf2f(src[(size_t)(l0 - 3) * D_IN_PROJ]) : 0.f;
  float x1 = (l0 >= 2) ? bf2f(src[(size_t)(l0 - 2) * D_IN_PROJ]) : 0.f;
  float x2 = (l0 >= 1) ? bf2f(src[(size_t)(l0 - 1) * D_IN_PROJ]) : 0.f;
  unsigned short* dst = xconv + ((size_t)(b * LSEQ + l0)) * CONV_DIM + c;
  #pragma unroll 4
  for (int i = 0; i < 128; ++i) {
    float x3 = bf2f(src[(size_t)(l0 + i) * D_IN_PROJ]);
    float acc = fmaf(w3, x3, fmaf(w2, x2, fmaf(w1, x1, fmaf(w0, x0, bia))));
    float s = acc / (1.f + expf(-acc));
    dst[(size_t)i * CONV_DIM] = f2bf(s);
    x0 = x1; x1 = x2; x2 = x3;
  }
}

// ---------------------------------------------------------------------------
// fused: dt = softplus(dtraw + bias); per-chunk cumsum of dt*A.
// ---------------------------------------------------------------------------
__global__ __launch_bounds__(256) void cumsum_kernel(
    const float* __restrict__ dtraw, const float* __restrict__ dt_bias,
    const float* __restrict__ A_log, float* __restrict__ dt_s,
    float* __restrict__ cumL) {
  int u = blockIdx.x * 4 + (threadIdx.x >> 6);
  int lane = threadIdx.x & 63;
  int h = u & 31;
  int bc = u >> 5;
  int row = bc * 64 + lane;
  float xr = dtraw[(size_t)row * 32 + h] + dt_bias[h];
  float dt = (xr > 20.f) ? xr : log1pf(expf(xr));
  dt_s[(size_t)row * NHEADS + h] = dt;
  float A = -expf(A_log[h]);
  float a = dt * A;
  #pragma unroll
  for (int off = 1; off < 64; off <<= 1) {
    float v = __shfl_up(a, off);
    if (lane >= off) a += v;
  }
  cumL[(size_t)u * 64 + lane] = a;
}

// ---------------------------------------------------------------------------
// chunk state: S^T[p][n] = sum_s w_s x[s][p] B[s][n]
// ---------------------------------------------------------------------------
__global__ __launch_bounds__(256) void chunkstate_kernel(
    const unsigned short* __restrict__ xconv, const float* __restrict__ dt_s,
    const float* __restrict__ cumL, unsigned short* __restrict__ S) {
  const int bi = blockIdx.x;
  const int h  = bi & 31;
  const int bc = bi >> 5;
  const int row0 = bc * 64;
  const int tid = threadIdx.x;

  __shared__ unsigned short sBT[128 * 64];   // [n][s]
  __shared__ unsigned short sXT[64 * 64];    // [p][s]  (w-weighted)
  __shared__ float sw[64];

  if (tid < 64) {
    float L   = cumL[(size_t)bi * 64 + tid];
    float L63 = cumL[(size_t)bi * 64 + 63];
    sw[tid] = dt_s[(size_t)(row0 + tid) * NHEADS + h] * expf(L63 - L);
  }
  __syncthreads();

  #pragma unroll
  for (int i = 0; i < 16; ++i) {
    int idx = tid + i * 256;
    int s = idx >> 6, n2 = idx & 63;
    unsigned int v = *reinterpret_cast<const unsigned int*>(
        &xconv[(size_t)(row0 + s) * CONV_DIM + D_INNER + n2 * 2]);
    lds_w16(sBT, n2 * 2 + 0, s, 64, (unsigned short)v);
    lds_w16(sBT, n2 * 2 + 1, s, 64, (unsigned short)(v >> 16));
  }
  #pragma unroll
  for (int i = 0; i < 16; ++i) {
    int idx = tid + i * 256;
    int s = idx >> 6, p = idx & 63;
    float xv = bf2f(xconv[(size_t)(row0 + s) * CONV_DIM + h * HEADDIM + p]);
    lds_w16(sXT, p, s, 64, f2bf(xv * sw[s]));
  }
  __syncthreads();

  const int w  = tid >> 6;
  const int l  = tid & 63;
  const int la = l & 15;
  const int lk = (l >> 4) * 8;

  f32x4 acc[8];
  #pragma unroll
  for (int i = 0; i < 8; ++i) acc[i] = (f32x4){0.f, 0.f, 0.f, 0.f};

  #pragma unroll
  for (int ks = 0; ks < 2; ++ks) {
    short8_t a = lds_frag(sXT, 16 * w + la, ks * 32 + lk, 64);
    #pragma unroll
    for (int ni = 0; ni < 8; ++ni) {
      short8_t b = lds_frag(sBT, ni * 16 + la, ks * 32 + lk, 64);
      acc[ni] = MFMA16(a, b, acc[ni]);
    }
  }

  unsigned short* dst = S + (size_t)bi * (HEADDIM * D_STATE);
  #pragma unroll
  for (int ni = 0; ni < 8; ++ni)
    #pragma unroll
    for (int r = 0; r < 4; ++r) {
      int p = 16 * w + (l >> 4) * 4 + r;
      int n = ni * 16 + la;
      dst[p * D_STATE + n] = f2bf(acc[ni][r]);
    }
}

// ---------------------------------------------------------------------------
// H recurrence, elementwise; in place S -> Hprev.
// ---------------------------------------------------------------------------
__global__ __launch_bounds__(256) void hscan_kernel(
    unsigned short* __restrict__ S, const float* __restrict__ cumL) {
  const int g  = blockIdx.x;
  const int bh = g >> 5;
  const int b  = bh >> 5;
  const int h  = bh & 31;
  const int e  = (g & 31) * 256 + threadIdx.x;

  float H = 0.f;
  #pragma unroll 4
  for (int c = 0; c < NC; ++c) {
    size_t u = (size_t)((b * NC + c) * NHEADS + h);
    float dA = expf(cumL[u * 64 + 63]);
    unsigned short sv = S[u * (HEADDIM * D_STATE) + e];
    S[u * (HEADDIM * D_STATE) + e] = f2bf(H);
    H = dA * H + bf2f(sv);
  }
}

// ---------------------------------------------------------------------------
// fused chunk kernel -> y (bf16)
// ---------------------------------------------------------------------------
__global__ __launch_bounds__(256) void chunk_kernel(
    const unsigned short* __restrict__ xconv, const float* __restrict__ dt_s,
    const float* __restrict__ cumL, const unsigned short* __restrict__ Hprev,
    const float* __restrict__ D_skip, unsigned short* __restrict__ y) {
  const int bi = blockIdx.x;
  const int h  = bi & 31;
  const int bc = bi >> 5;
  const int row0 = bc * 64;
  const int tid = threadIdx.x;

  __shared__ unsigned short sC[64 * 128];
  __shared__ unsigned short sB[64 * 128];
  __shared__ unsigned short sXT[64 * 64];
  __shared__ unsigned short sP[64 * 64];
  __shared__ float sL[64], sdt[64], seL[64];

  if (tid < 64) {
    float L = cumL[(size_t)bi * 64 + tid];
    sL[tid]  = L;
    seL[tid] = expf(L);
    sdt[tid] = dt_s[(size_t)(row0 + tid) * NHEADS + h];
  }

  #pragma unroll
  for (int i = 0; i < 8; ++i) {
    int idx = tid + i * 256;
    int r = idx >> 5, q = idx & 31;
    short8_t v = *reinterpret_cast<const short8_t*>(
        &xconv[(size_t)(row0 + r) * CONV_DIM + D_INNER + q * 8]);
    unsigned int u0 = (unsigned int)(unsigned short)v[0] |
                      ((unsigned int)(unsigned short)v[1] << 16);
    unsigned int u1 = (unsigned int)(unsigned short)v[2] |
                      ((unsigned int)(unsigned short)v[3] << 16);
    unsigned int u2 = (unsigned int)(unsigned short)v[4] |
                      ((unsigned int)(unsigned short)v[5] << 16);
    unsigned int u3 = (unsigned int)(unsigned short)v[6] |
                      ((unsigned int)(unsigned short)v[7] << 16);
    unsigned short* dstb = (q < 16) ? sB : sC;
    int cq = (q & 15) * 8;
    lds_w32(dstb, r, cq + 0, 128, u0);
    lds_w32(dstb, r, cq + 2, 128, u1);
    lds_w32(dstb, r, cq + 4, 128, u2);
    lds_w32(dstb, r, cq + 6, 128, u3);
  }
  #pragma unroll
  for (int i = 0; i < 16; ++i) {
    int idx = tid + i * 256;
    int s = idx >> 6, p = idx & 63;
    lds_w16(sXT, p, s, 64,
            xconv[(size_t)(row0 + s) * CONV_DIM + h * HEADDIM + p]);
  }
  __syncthreads();

  const int w  = tid >> 6;
  const int l  = tid & 63;
  const int la = l & 15;
  const int lk = (l >> 4) * 8;
  const int t0 = 16 * w;

  f32x4 g[4];
  #pragma unroll
  for (int i = 0; i < 4; ++i) g[i] = (f32x4){0.f, 0.f, 0.f, 0.f};
  #pragma unroll
  for (int ks = 0; ks < 4; ++ks) {
    short8_t a = lds_frag(sC, t0 + la, ks * 32 + lk, 128);
    #pragma unroll
    for (int si = 0; si < 4; ++si) {
      short8_t b = lds_frag(sB, si * 16 + la, ks * 32 + lk, 128);
      g[si] = MFMA16(a, b, g[si]);
    }
  }
  #pragma unroll
  for (int si = 0; si < 4; ++si)
    #pragma unroll
    for (int r = 0; r < 4; ++r) {
      int t = t0 + (l >> 4) * 4 + r;
      int s = si * 16 + la;
      float m = 0.f;
      if (s <= t) m = expf(sL[t] - sL[s]) * sdt[s] * g[si][r];
      lds_w16(sP, t, s, 64, f2bf(m));
    }
  __syncthreads();

  f32x4 o[4];
  #pragma unroll
  for (int i = 0; i < 4; ++i) o[i] = (f32x4){0.f, 0.f, 0.f, 0.f};

  const unsigned short* hb = Hprev + (size_t)bi * (HEADDIM * D_STATE);
  #pragma unroll
  for (int ks = 0; ks < 4; ++ks) {
    short8_t a = lds_frag(sC, t0 + la, ks * 32 + lk, 128);
    #pragma unroll
    for (int si = 0; si < 4; ++si) {
      int p = si * 16 + la;
      short8_t b = *reinterpret_cast<const short8_t*>(
          &hb[p * D_STATE + ks * 32 + lk]);
      o[si] = MFMA16(a, b, o[si]);
    }
  }
  #pragma unroll
  for (int si = 0; si < 4; ++si)
    #pragma unroll
    for (int r = 0; r < 4; ++r) {
      int t = t0 + (l >> 4) * 4 + r;
      o[si][r] *= seL[t];
    }
  #pragma unroll
  for (int ks = 0; ks < 2; ++ks) {
    short8_t a = lds_frag(sP, t0 + la, ks * 32 + lk, 64);
    #pragma unroll
    for (int si = 0; si < 4; ++si) {
      short8_t b = lds_frag(sXT, si * 16 + la, ks * 32 + lk, 64);
      o[si] = MFMA16(a, b, o[si]);
    }
  }
  const float Dh = D_skip[h];
  #pragma unroll
  for (int si = 0; si < 4; ++si)
    #pragma unroll
    for (int r = 0; r < 4; ++r) {
      int t = t0 + (l >> 4) * 4 + r;
      int p = si * 16 + la;
      float xv = bf2f(lds_r16(sXT, p, t, 64));
      y[(size_t)(row0 + t) * D_INNER + h * HEADDIM + p] = f2bf(o[si][r] + Dh * xv);
    }
}

// ---------------------------------------------------------------------------
// y(bf16) = y * silu(z bf16); RMSNorm; in-place, short8 vectorized
// ---------------------------------------------------------------------------
__global__ __launch_bounds__(256) void gate_rms_kernel(
    unsigned short* __restrict__ y, const unsigned short* __restrict__ zxb,
    const float* __restrict__ norm_w) {
  const int row = blockIdx.x;
  const int tid = threadIdx.x;
  short8_t zv = *reinterpret_cast<const short8_t*>(
      &zxb[(size_t)row * D_IN_PROJ + tid * 8]);
  short8_t yv = *reinterpret_cast<short8_t*>(
      &y[(size_t)row * D_INNER + tid * 8]);
  float v[8];
  float acc = 0.f;
  #pragma unroll
  for (int i = 0; i < 8; ++i) {
    float z  = bf2f((unsigned short)zv[i]);
    float ys = bf2f((unsigned short)yv[i]);
    float gz = z / (1.f + expf(-z));
    float val = ys * gz;
    v[i] = val;
    acc = fmaf(val, val, acc);
  }
  #pragma unroll
  for (int off = 32; off; off >>= 1) acc += __shfl_xor(acc, off);
  __shared__ float wsum[4];
  if ((tid & 63) == 0) wsum[tid >> 6] = acc;
  __syncthreads();
  float total = wsum[0] + wsum[1] + wsum[2] + wsum[3];
  float scale = rsqrtf(total / (float)D_INNER + 1e-5f);
  short8_t o;
  #pragma unroll
  for (int i = 0; i < 8; ++i)
    o[i] = (short)f2bf(v[i] * scale * norm_w[tid * 8 + i]);
  *reinterpret_cast<short8_t*>(&y[(size_t)row * D_INNER + tid * 8]) = o;
}

// ---------------------------------------------------------------------------
// LayerNorm + residual
// ---------------------------------------------------------------------------
__global__ __launch_bounds__(256) void ln_kernel(
    const float* __restrict__ o, const float* __restrict__ x,
    const float* __restrict__ lng, const float* __restrict__ lnb,
    float* __restrict__ out) {
  const int row = blockIdx.x;
  const int tid = threadIdx.x;
  float v[4];
  float s = 0.f, s2 = 0.f;
  #pragma unroll
  for (int i = 0; i < 4; ++i) {
    int d = i * 256 + tid;
    float t = o[(size_t)row * D_MODEL + d];
    v[i] = t;
    s += t;
    s2 = fmaf(t, t, s2);
  }
  #pragma unroll
  for (int off = 32; off; off >>= 1) {
    s  += __shfl_xor(s, off);
    s2 += __shfl_xor(s2, off);
  }
  __shared__ float sa[4], sb[4];
  if ((tid & 63) == 0) { sa[tid >> 6] = s; sb[tid >> 6] = s2; }
  __syncthreads();
  s  = sa[0] + sa[1] + sa[2] + sa[3];
  s2 = sb[0] + sb[1] + sb[2] + sb[3];
  float mu  = s / (float)D_MODEL;
  float var = s2 / (float)D_MODEL - mu * mu;
  float inv = rsqrtf(var + 1e-5f);
  #pragma unroll
  for (int i = 0; i < 4; ++i) {
    int d = i * 256 + tid;
    out[(size_t)row * D_MODEL + d] =
        (v[i] - mu) * inv * lng[d] + lnb[d] + x[(size_t)row * D_MODEL + d];
  }
}

// ---------------------------------------------------------------------------
extern "C" void kernel_launch(void* const* d_in, const int* in_sizes, int n_in,
                              void* d_out, int out_size, void* d_ws, size_t ws_size,
                              hipStream_t stream) {
  const float* x         = (const float*)d_in[0];
  const float* in_proj_w = (const float*)d_in[1];
  const float* conv_w    = (const float*)d_in[2];
  const float* conv_b    = (const float*)d_in[3];
  const float* dt_bias   = (const float*)d_in[4];
  const float* A_log     = (const float*)d_in[5];
  const float* D_skip    = (const float*)d_in[6];
  const float* norm_w    = (const float*)d_in[7];
  const float* out_w     = (const float*)d_in[8];
  const float* ln_g      = (const float*)d_in[9];
  const float* ln_b      = (const float*)d_in[10];
  float* out = (float*)d_out;

  char* ws = (char*)d_ws;
  unsigned short* zxb   = (unsigned short*)ws;                       // 4096*4384 bf16
  float* outpre         = (float*)ws;                                // alias (dead z)
  char* p = ws + (size_t)NROWS * D_IN_PROJ * 2;
  float* dtraw = (float*)p;            p += (size_t)NROWS * 32 * 4;
  float* dt_s  = (float*)p;            p += (size_t)NROWS * 32 * 4;
  float* cumL  = (float*)p;            p += (size_t)BATCH * NC * NHEADS * 64 * 4;
  unsigned short* xconv = (unsigned short*)p;  p += (size_t)NROWS * CONV_DIM * 2;
  unsigned short* schp  = (unsigned short*)p;  p += (size_t)BATCH * NC * NHEADS * HEADDIM * D_STATE * 2;
  unsigned short* ybuf  = (unsigned short*)p;  p += (size_t)NROWS * D_INNER * 2;
  unsigned short* xbf   = (unsigned short*)p;  p += (size_t)NROWS * D_MODEL * 2;
  unsigned short* wbf   = (unsigned short*)p;  p += (size_t)NPAD * D_MODEL * 2;
  unsigned short* owbf  = (unsigned short*)p;

  // 64KB dynamic LDS for the double-buffered GEMMs
  (void)hipFuncSetAttribute(reinterpret_cast<const void*>(&gemm_db<1>),
                            hipFuncAttributeMaxDynamicSharedMemorySize, 65536);
  (void)hipFuncSetAttribute(reinterpret_cast<const void*>(&gemm_db<0>),
                            hipFuncAttributeMaxDynamicSharedMemorySize, 65536);

  // 0. converts (fused into one launch)
  {
    const long n1 = (long)NROWS * D_MODEL / 8;
    const long n2 = (long)NPAD * D_MODEL / 8;
    const long n3 = (long)D_MODEL * D_INNER / 8;
    int nblk = (int)((n1 + n2 + n3) / 256);
    cvt_all_kernel<<<dim3(nblk), dim3(256), 0, stream>>>(
        x, in_proj_w, out_w, xbf, wbf, owbf);
  }

  // 1. in_proj GEMM (double-buffered, bf16 out + fp32 dtraw side-channel)
  gemm_db<1><<<dim3(NPAD / 128, NROWS / 128), dim3(256), 65536, stream>>>(
      xbf, wbf, zxb, dtraw, D_IN_PROJ, D_MODEL);

  // 2. conv + silu (bf16 in/out, l-strip)
  conv_silu_kernel<<<dim3(CONV_DIM / 256, LSEQ / 128, BATCH), dim3(256), 0, stream>>>(
      zxb, conv_w, conv_b, xconv);

  // 3. fused dt + per-chunk cumsum
  cumsum_kernel<<<dim3(BATCH * NC * NHEADS / 4), dim3(256), 0, stream>>>(
      dtraw, dt_bias, A_log, dt_s, cumL);

  // 4. chunk states S (bf16)
  chunkstate_kernel<<<dim3(BATCH * NC * NHEADS), dim3(256), 0, stream>>>(
      xconv, dt_s, cumL, schp);

  // 5. H recurrence (in place S -> Hprev)
  hscan_kernel<<<dim3(BATCH * NHEADS * 32), dim3(256), 0, stream>>>(
      schp, cumL);

  // 6. fused chunk kernel (writes ybuf bf16)
  chunk_kernel<<<dim3(BATCH * NC * NHEADS), dim3(256), 0, stream>>>(
      xconv, dt_s, cumL, schp, D_skip, ybuf);

  // 7. gate + rmsnorm (in-place bf16)
  gate_rms_kernel<<<dim3(NROWS), dim3(256), 0, stream>>>(
      ybuf, zxb, norm_w);

  // 8. out_proj GEMM (fp32 out into outpre, aliasing dead zxb)
  gemm_db<0><<<dim3(D_MODEL / 128, NROWS / 128), dim3(256), 65536, stream>>>(
      ybuf, owbf, outpre, nullptr, D_MODEL, D_INNER);

  // 9. layernorm + residual
  ln_kernel<<<dim3(NROWS), dim3(256), 0, stream>>>(
      outpre, x, ln_g, ln_b, out);
}